// Round 15
// baseline (234.379 us; speedup 1.0000x reference)
//
#include <hip/hip_runtime.h>
#include <hip/hip_fp16.h>

constexpr int NN  = 100000;
constexpr int NE  = 3200000;
constexpr int CIN = 128;
constexpr int CH  = 16;   // hidden
constexpr int CO  = 64;   // out

constexpr int NBKT  = 391;    // ceil(NN/256): bucket = dest >> 8
constexpr int CHUNK = 4096;   // edges per block in the partition pass
constexpr int NBLK  = 782;    // ceil(NE/CHUNK)
constexpr int BCAP  = 12288;  // fixed slots per bucket in ebuf (mean 8183, sigma 90)
constexpr int PCAP  = 13060;  // fixed padded slots per bucket in csr_rid (4-aligned)
constexpr int SEGCAP = 12288; // LDS staging cap for k_fine (48 KB) == BCAP
constexpr int INDCAP = 4096;  // LDS index cap per 64-node gather block (16 KB)
constexpr int GBLK   = 1563;  // ceil(NN/64)

// ext-vector types: __builtin_nontemporal_* accepts these (not HIP_vector_type)
typedef int   ei4 __attribute__((ext_vector_type(4)));
typedef float ef4 __attribute__((ext_vector_type(4)));

__device__ __forceinline__ int4 ntl_i4(const int4* p) {
    ei4 v = __builtin_nontemporal_load((const ei4*)p);
    return make_int4(v.x, v.y, v.z, v.w);
}
__device__ __forceinline__ float4 ntl_f4(const float4* p) {
    ef4 v = __builtin_nontemporal_load((const ef4*)p);
    return make_float4(v.x, v.y, v.z, v.w);
}
#define NTL(p)     __builtin_nontemporal_load(p)
#define NTS(v, p)  __builtin_nontemporal_store(v, p)

// ---- CSR build: fixed-capacity buckets, single edge pass -----------------

__global__ void k_init(int* __restrict__ gcur) {
    int t = threadIdx.x;
    if (t < NBKT) gcur[t] = t * BCAP;
}

// chunk -> LDS count -> scan -> atomic run-reservation -> LDS bucket-sort
// -> run-contiguous copy-out into fixed bucket regions (all streams NT)
__global__ void __launch_bounds__(512) k_part(const int* __restrict__ rows,
                                              const int* __restrict__ cols,
                                              int* __restrict__ gcur,
                                              int* __restrict__ ebuf) {
    __shared__ int sh[512];
    __shared__ int run[NBKT];
    __shared__ int tgt[NBKT];
    __shared__ int seg[CHUNK];
    __shared__ int gaddr[CHUNK];
    int t = threadIdx.x, blk = blockIdx.x;
    for (int i = t; i < NBKT; i += 512) run[i] = 0;
    __syncthreads();
    const int4* c4 = (const int4*)cols;
    const int4* r4 = (const int4*)rows;
    int base = blk * (CHUNK / 4);
#pragma unroll
    for (int j = 0; j < 2; ++j) {
        int idx = base + j * 512 + t;
        if (idx < NE / 4) {
            int4 c = ntl_i4(&c4[idx]);
            atomicAdd(&run[c.x >> 8], 1); atomicAdd(&run[c.y >> 8], 1);
            atomicAdd(&run[c.z >> 8], 1); atomicAdd(&run[c.w >> 8], 1);
        }
    }
    __syncthreads();
    int v = (t < NBKT) ? run[t] : 0;
    sh[t] = v;
    __syncthreads();
    for (int off = 1; off < 512; off <<= 1) {
        int a = (t >= off) ? sh[t - off] : 0;
        __syncthreads();
        sh[t] += a;
        __syncthreads();
    }
    if (t < NBKT) {
        int excl = sh[t] - v;
        run[t] = excl;
        tgt[t] = (v ? atomicAdd(&gcur[t], v) : 0) - excl;
    }
    __syncthreads();
#pragma unroll
    for (int j = 0; j < 2; ++j) {
        int idx = base + j * 512 + t;
        if (idx < NE / 4) {
            int4 r = ntl_i4(&r4[idx]);
            int4 c = ntl_i4(&c4[idx]);
            int b0, p;
            b0 = c.x >> 8; p = atomicAdd(&run[b0], 1); seg[p] = r.x | ((c.x & 255) << 17); gaddr[p] = tgt[b0] + p;
            b0 = c.y >> 8; p = atomicAdd(&run[b0], 1); seg[p] = r.y | ((c.y & 255) << 17); gaddr[p] = tgt[b0] + p;
            b0 = c.z >> 8; p = atomicAdd(&run[b0], 1); seg[p] = r.z | ((c.z & 255) << 17); gaddr[p] = tgt[b0] + p;
            b0 = c.w >> 8; p = atomicAdd(&run[b0], 1); seg[p] = r.w | ((c.w & 255) << 17); gaddr[p] = tgt[b0] + p;
        }
    }
    __syncthreads();
    int n = min(CHUNK, NE - blk * CHUNK);
    for (int j = t; j < n; j += 512) NTS(seg[j], &ebuf[gaddr[j]]);
}

// one block per bucket: LDS-staged count -> padded scan -> place -> pad-fill.
__global__ void __launch_bounds__(256) k_fine(const int* __restrict__ ebuf,
                                              const int* __restrict__ gcur,
                                              int* __restrict__ cursor,
                                              int* __restrict__ cnt,
                                              float* __restrict__ dis,
                                              int* __restrict__ csr_rid) {
    __shared__ int seg[SEGCAP];
    __shared__ int scnt[256], sloc[256], run[256];
    int t = threadIdx.x, b = blockIdx.x;
    int base = b * BCAP;
    int n = gcur[b] - base;
    bool inlds = (n <= SEGCAP);
    scnt[t] = 0;
    if (inlds) for (int i = t; i < n; i += 256) seg[i] = NTL(&ebuf[base + i]);
    __syncthreads();
    if (inlds) for (int i = t; i < n; i += 256) atomicAdd(&scnt[seg[i] >> 17], 1);
    else       for (int i = t; i < n; i += 256) atomicAdd(&scnt[NTL(&ebuf[base + i]) >> 17], 1);
    __syncthreads();
    int v = scnt[t];
    int v4 = (v + 3) & ~3;
    sloc[t] = v4;
    __syncthreads();
    for (int off = 1; off < 256; off <<= 1) {
        int a = (t >= off) ? sloc[t - off] : 0;
        __syncthreads();
        sloc[t] += a;
        __syncthreads();
    }
    int cur = b * PCAP + (sloc[t] - v4);
    int c = b * 256 + t;
    if (c < NN) {
        cursor[c] = cur;
        cnt[c]    = v;
        dis[c]    = rsqrtf((float)(v + 1));
    }
    run[t] = cur;
    __syncthreads();
    if (inlds) {
        for (int i = t; i < n; i += 256) {
            int pk = seg[i];
            int pos = atomicAdd(&run[pk >> 17], 1);
            NTS(pk & 0x1FFFF, &csr_rid[pos]);
        }
    } else {
        for (int i = t; i < n; i += 256) {
            int pk = NTL(&ebuf[base + i]);
            int pos = atomicAdd(&run[pk >> 17], 1);
            NTS(pk & 0x1FFFF, &csr_rid[pos]);
        }
    }
    __syncthreads();
    if (c < NN) {
        int p = cur + v, p4 = cur + v4;
        for (; p < p4; ++p) NTS(NN, &csr_rid[p]);  // dummy -> zero feature row
    }
}

// ---- layer math ---------------------------------------------------------

// gh (fp16) = dis[node] * (x @ W1); x streamed NT (single use)
__global__ void __launch_bounds__(256) k_gemm1s(const float* __restrict__ x,
                                                const float* __restrict__ W1,
                                                const float* __restrict__ dis,
                                                __half* __restrict__ gh) {
    __shared__ float xs[32][CIN + 1];
    __shared__ float ws[CIN][CH];
    int t = threadIdx.x;
    int base = blockIdx.x * 32;                  // 100000 = 32*3125
    for (int i = t; i < CIN * CH; i += 256) ws[i >> 4][i & 15] = W1[i];
    const float4* xv = (const float4*)(x + (size_t)base * CIN);
    for (int i = t; i < 32 * CIN / 4; i += 256) {
        float4 v = ntl_f4(&xv[i]);
        int r = i >> 5, cq = i & 31;
        xs[r][cq * 4 + 0] = v.x; xs[r][cq * 4 + 1] = v.y;
        xs[r][cq * 4 + 2] = v.z; xs[r][cq * 4 + 3] = v.w;
    }
    __syncthreads();
    int node = t >> 3;
    int c0 = (t & 7) * 2;
    float a0 = 0.f, a1 = 0.f;
#pragma unroll 8
    for (int k = 0; k < CIN; ++k) {
        float xk = xs[node][k];
        a0 += xk * ws[k][c0];
        a1 += xk * ws[k][c0 + 1];
    }
    float d = dis[base + node];
    ((__half2*)gh)[((size_t)(base + node) * CH + c0) >> 1] = __floats2half2_rn(a0 * d, a1 * d);
}

__global__ void k_zrow(__half* __restrict__ gh, __half* __restrict__ g2h) {
    int t = threadIdx.x;
    if (t < CH) {
        gh [(size_t)NN * CH + t] = __float2half(0.f);
        g2h[(size_t)NN * CH + t] = __float2half(0.f);
    }
}

// add 8 fp16 channels (one float4 = 4 half2) into acc[8]
__device__ __forceinline__ void acc_h8(float4 raw, float* acc) {
    __half2 h0 = *(__half2*)&raw.x, h1 = *(__half2*)&raw.y;
    __half2 h2 = *(__half2*)&raw.z, h3 = *(__half2*)&raw.w;
    float2 f0 = __half22float2(h0), f1 = __half22float2(h1);
    float2 f2 = __half22float2(h2), f3 = __half22float2(h3);
    acc[0] += f0.x; acc[1] += f0.y; acc[2] += f1.x; acc[3] += f1.y;
    acc[4] += f2.x; acc[5] += f2.y; acc[6] += f3.x; acc[7] += f3.y;
}

// core accumulation over one node's edges given an int4 index stream
template <typename I4>
__device__ __forceinline__ void gather_loop(const I4 I, int nb, int h, int q,
                                            const float4* __restrict__ g8,
                                            float* acc) {
    int b = h;
    for (; b + 2 < nb; b += 4) {
        int4 i0 = I[b], i1 = I[b + 2];
        float4 v0 = g8[i0.x * 2 + q], v1 = g8[i0.y * 2 + q];
        float4 v2 = g8[i0.z * 2 + q], v3 = g8[i0.w * 2 + q];
        float4 w0 = g8[i1.x * 2 + q], w1 = g8[i1.y * 2 + q];
        float4 w2 = g8[i1.z * 2 + q], w3 = g8[i1.w * 2 + q];
        acc_h8(v0, acc); acc_h8(v1, acc); acc_h8(v2, acc); acc_h8(v3, acc);
        acc_h8(w0, acc); acc_h8(w1, acc); acc_h8(w2, acc); acc_h8(w3, acc);
    }
    for (; b < nb; b += 2) {
        int4 i0 = I[b];
        float4 v0 = g8[i0.x * 2 + q], v1 = g8[i0.y * 2 + q];
        float4 v2 = g8[i0.z * 2 + q], v3 = g8[i0.w * 2 + q];
        acc_h8(v0, acc); acc_h8(v1, acc); acc_h8(v2, acc); acc_h8(v3, acc);
    }
}

// 64 nodes/block, indices staged in LDS (NT from global)
__global__ void __launch_bounds__(256) k_gather1(const int* __restrict__ csr_rid,
                                                 const int* __restrict__ cursor,
                                                 const int* __restrict__ cnt,
                                                 const float* __restrict__ dis,
                                                 const __half* __restrict__ gh,
                                                 const float* __restrict__ b1,
                                                 __half* __restrict__ g2h) {
    __shared__ int ind[INDCAP];
    int t = threadIdx.x;
    int nbase = blockIdx.x * 64;
    int last  = min(nbase + 63, NN - 1);
    int start_all = cursor[nbase];
    int end_all   = cursor[last] + ((cnt[last] + 3) & ~3);
    int n_all = end_all - start_all;
    bool lds_ok = (n_all <= INDCAP);
    if (lds_ok) for (int i = t; i < n_all; i += 256) ind[i] = NTL(&csr_rid[start_all + i]);
    __syncthreads();
    int nl = t >> 2, q = t & 1, h = (t >> 1) & 1;
    int node = nbase + nl;
    if (node < NN) {
        const float4* g8 = (const float4*)gh;
        int myStart = cursor[node];
        int nb = (cnt[node] + 3) >> 2;
        float acc[8] = {0.f, 0.f, 0.f, 0.f, 0.f, 0.f, 0.f, 0.f};
        if (lds_ok) gather_loop((const int4*)&ind[myStart - start_all], nb, h, q, g8, acc);
        else        gather_loop((const int4*)(csr_rid + myStart),        nb, h, q, g8, acc);
#pragma unroll
        for (int j = 0; j < 8; ++j) acc[j] += __shfl_xor(acc[j], 2);
        if (h == 0) {
            acc_h8(g8[node * 2 + q], acc);       // self-loop
            float d = dis[node];
            const float4* b4 = (const float4*)b1;
            float4 bb0 = b4[q * 2], bb1 = b4[q * 2 + 1];
            float r0 = d * fmaxf(d * acc[0] + bb0.x, 0.f);
            float r1 = d * fmaxf(d * acc[1] + bb0.y, 0.f);
            float r2 = d * fmaxf(d * acc[2] + bb0.z, 0.f);
            float r3 = d * fmaxf(d * acc[3] + bb0.w, 0.f);
            float r4 = d * fmaxf(d * acc[4] + bb1.x, 0.f);
            float r5 = d * fmaxf(d * acc[5] + bb1.y, 0.f);
            float r6 = d * fmaxf(d * acc[6] + bb1.z, 0.f);
            float r7 = d * fmaxf(d * acc[7] + bb1.w, 0.f);
            __half2 p0 = __floats2half2_rn(r0, r1), p1 = __floats2half2_rn(r2, r3);
            __half2 p2 = __floats2half2_rn(r4, r5), p3 = __floats2half2_rn(r6, r7);
            uint4 wv;
            wv.x = *(unsigned int*)&p0; wv.y = *(unsigned int*)&p1;
            wv.z = *(unsigned int*)&p2; wv.w = *(unsigned int*)&p3;
            ((uint4*)g2h)[node * 2 + q] = wv;    // cached: gather2 reuses
        }
    }
}

// layer-2 gather fused with final GEMM + sigmoid; out streamed NT
__global__ void __launch_bounds__(256) k_gather2(const int* __restrict__ csr_rid,
                                                 const int* __restrict__ cursor,
                                                 const int* __restrict__ cnt,
                                                 const float* __restrict__ dis,
                                                 const __half* __restrict__ g2h,
                                                 const float* __restrict__ W2,
                                                 const float* __restrict__ b2,
                                                 float* __restrict__ out) {
    __shared__ int ind[INDCAP];
    __shared__ float vs[64][CH + 1];
    __shared__ float w2s[CH][CO];
    int t = threadIdx.x;
    for (int i = t; i < CH * CO; i += 256) w2s[i >> 6][i & 63] = W2[i];
    int nbase = blockIdx.x * 64;
    int last  = min(nbase + 63, NN - 1);
    int start_all = cursor[nbase];
    int end_all   = cursor[last] + ((cnt[last] + 3) & ~3);
    int n_all = end_all - start_all;
    bool lds_ok = (n_all <= INDCAP);
    if (lds_ok) for (int i = t; i < n_all; i += 256) ind[i] = NTL(&csr_rid[start_all + i]);
    __syncthreads();
    int nl = t >> 2, q = t & 1, h = (t >> 1) & 1;
    int node = nbase + nl;
    if (node < NN) {
        const float4* g8 = (const float4*)g2h;
        int myStart = cursor[node];
        int nb = (cnt[node] + 3) >> 2;
        float acc[8] = {0.f, 0.f, 0.f, 0.f, 0.f, 0.f, 0.f, 0.f};
        if (lds_ok) gather_loop((const int4*)&ind[myStart - start_all], nb, h, q, g8, acc);
        else        gather_loop((const int4*)(csr_rid + myStart),        nb, h, q, g8, acc);
#pragma unroll
        for (int j = 0; j < 8; ++j) acc[j] += __shfl_xor(acc[j], 2);
        if (h == 0) {
            acc_h8(g8[node * 2 + q], acc);       // self-loop
            float d = dis[node];
#pragma unroll
            for (int j = 0; j < 8; ++j) vs[nl][q * 8 + j] = d * acc[j];
        }
    }
    __syncthreads();
    int o = t & 63, grp = t >> 6;                // 4 groups x 16 nodes each
#pragma unroll
    for (int k = 0; k < 16; ++k) {
        int nl2 = grp * 16 + k;
        int node2 = nbase + nl2;
        if (node2 >= NN) break;
        float acc = b2[o];
#pragma unroll
        for (int c = 0; c < CH; ++c) acc += vs[nl2][c] * w2s[c][o];
        NTS(1.0f / (1.0f + __expf(-acc)), &out[(size_t)node2 * CO + o]);
    }
}

extern "C" void kernel_launch(void* const* d_in, const int* in_sizes, int n_in,
                              void* d_out, int out_size, void* d_ws, size_t ws_size,
                              hipStream_t stream) {
    const float* x  = (const float*)d_in[0];
    const int*   ei = (const int*)d_in[1];
    const float* W1 = (const float*)d_in[2];
    const float* b1 = (const float*)d_in[3];
    const float* W2 = (const float*)d_in[4];
    const float* b2 = (const float*)d_in[5];
    float* out = (float*)d_out;

    const int* rows = ei;
    const int* cols = ei + NE;

    char* w = (char*)d_ws;
    int*   cursor  = (int*)w;                 w += 100096 * 4;
    int*   cnt     = (int*)w;                 w += 100096 * 4;
    float* dis     = (float*)w;               w += 100096 * 4;
    int*   gcur    = (int*)w;                 w += 512 * 4;
    int*   ebuf    = (int*)w;                 w += (size_t)NBKT * BCAP * 4;   // 19.2 MB
    int*   csr_rid = (int*)w;                 // NBKT * PCAP ints = 20.4 MB
    // fp16 feature tables alias ebuf (ebuf dead after k_fine); NN+1 rows each
    __half* gh  = (__half*)ebuf;
    __half* g2h = gh + (size_t)(NN + 1) * CH;

    k_init   <<<1,    512, 0, stream>>>(gcur);
    k_part   <<<NBLK, 512, 0, stream>>>(rows, cols, gcur, ebuf);
    k_fine   <<<NBKT, 256, 0, stream>>>(ebuf, gcur, cursor, cnt, dis, csr_rid);
    k_gemm1s <<<NN / 32, 256, 0, stream>>>(x, W1, dis, gh);
    k_zrow   <<<1, 64, 0, stream>>>(gh, g2h);
    k_gather1<<<GBLK, 256, 0, stream>>>(csr_rid, cursor, cnt, dis, gh, b1, g2h);
    k_gather2<<<GBLK, 256, 0, stream>>>(csr_rid, cursor, cnt, dis, g2h, W2, b2, out);
}

// Round 16
// 149.873 us; speedup vs baseline: 1.5639x; 1.5639x over previous
//
#include <hip/hip_runtime.h>
#include <hip/hip_fp16.h>

constexpr int NN  = 100000;
constexpr int NE  = 3200000;
constexpr int CIN = 128;
constexpr int CH  = 16;   // hidden
constexpr int CO  = 64;   // out

constexpr int NBKT  = 391;    // ceil(NN/256): bucket = dest >> 8
constexpr int CHUNK = 4096;   // edges per block in the partition pass
constexpr int NBLK  = 782;    // ceil(NE/CHUNK)
constexpr int BCAP  = 12288;  // fixed slots per bucket in ebuf (mean 8183, sigma 90)
constexpr int PCAP  = 13060;  // fixed padded slots per bucket in csr_rid (4-aligned)
constexpr int SEGCAP = 12288; // LDS staging cap for k_fine (48 KB) == BCAP
constexpr int INDCAP = 4096;  // LDS index cap per 64-node gather block (16 KB)
constexpr int GBLK   = 1563;  // ceil(NN/64)

// ext-vector types: __builtin_nontemporal_* accepts these (not HIP_vector_type)
typedef int   ei4 __attribute__((ext_vector_type(4)));
typedef float ef4 __attribute__((ext_vector_type(4)));

__device__ __forceinline__ int4 ntl_i4(const int4* p) {
    ei4 v = __builtin_nontemporal_load((const ei4*)p);
    return make_int4(v.x, v.y, v.z, v.w);
}
__device__ __forceinline__ float4 ntl_f4(const float4* p) {
    ef4 v = __builtin_nontemporal_load((const ef4*)p);
    return make_float4(v.x, v.y, v.z, v.w);
}
#define NTL(p)     __builtin_nontemporal_load(p)
#define NTS(v, p)  __builtin_nontemporal_store(v, p)

// ---- CSR build: fixed-capacity buckets, single edge pass -----------------

__global__ void k_init(int* __restrict__ gcur) {
    int t = threadIdx.x;
    if (t < NBKT) gcur[t] = t * BCAP;
}

// chunk -> LDS count -> scan -> atomic run-reservation -> LDS bucket-sort
// -> run-contiguous copy-out (NT loads for streams; PLAIN stores so L2 merges)
__global__ void __launch_bounds__(512) k_part(const int* __restrict__ rows,
                                              const int* __restrict__ cols,
                                              int* __restrict__ gcur,
                                              int* __restrict__ ebuf) {
    __shared__ int sh[512];
    __shared__ int run[NBKT];
    __shared__ int tgt[NBKT];
    __shared__ int seg[CHUNK];
    __shared__ int gaddr[CHUNK];
    int t = threadIdx.x, blk = blockIdx.x;
    for (int i = t; i < NBKT; i += 512) run[i] = 0;
    __syncthreads();
    const int4* c4 = (const int4*)cols;
    const int4* r4 = (const int4*)rows;
    int base = blk * (CHUNK / 4);
#pragma unroll
    for (int j = 0; j < 2; ++j) {
        int idx = base + j * 512 + t;
        if (idx < NE / 4) {
            int4 c = ntl_i4(&c4[idx]);
            atomicAdd(&run[c.x >> 8], 1); atomicAdd(&run[c.y >> 8], 1);
            atomicAdd(&run[c.z >> 8], 1); atomicAdd(&run[c.w >> 8], 1);
        }
    }
    __syncthreads();
    int v = (t < NBKT) ? run[t] : 0;
    sh[t] = v;
    __syncthreads();
    for (int off = 1; off < 512; off <<= 1) {
        int a = (t >= off) ? sh[t - off] : 0;
        __syncthreads();
        sh[t] += a;
        __syncthreads();
    }
    if (t < NBKT) {
        int excl = sh[t] - v;
        run[t] = excl;
        tgt[t] = (v ? atomicAdd(&gcur[t], v) : 0) - excl;
    }
    __syncthreads();
#pragma unroll
    for (int j = 0; j < 2; ++j) {
        int idx = base + j * 512 + t;
        if (idx < NE / 4) {
            int4 r = ntl_i4(&r4[idx]);
            int4 c = ntl_i4(&c4[idx]);
            int b0, p;
            b0 = c.x >> 8; p = atomicAdd(&run[b0], 1); seg[p] = r.x | ((c.x & 255) << 17); gaddr[p] = tgt[b0] + p;
            b0 = c.y >> 8; p = atomicAdd(&run[b0], 1); seg[p] = r.y | ((c.y & 255) << 17); gaddr[p] = tgt[b0] + p;
            b0 = c.z >> 8; p = atomicAdd(&run[b0], 1); seg[p] = r.z | ((c.z & 255) << 17); gaddr[p] = tgt[b0] + p;
            b0 = c.w >> 8; p = atomicAdd(&run[b0], 1); seg[p] = r.w | ((c.w & 255) << 17); gaddr[p] = tgt[b0] + p;
        }
    }
    __syncthreads();
    int n = min(CHUNK, NE - blk * CHUNK);
    for (int j = t; j < n; j += 512) ebuf[gaddr[j]] = seg[j];   // plain: L2 merges runs
}

// one block per bucket: LDS-staged count -> padded scan -> place -> pad-fill.
__global__ void __launch_bounds__(256) k_fine(const int* __restrict__ ebuf,
                                              const int* __restrict__ gcur,
                                              int* __restrict__ cursor,
                                              int* __restrict__ cnt,
                                              float* __restrict__ dis,
                                              int* __restrict__ csr_rid) {
    __shared__ int seg[SEGCAP];
    __shared__ int scnt[256], sloc[256], run[256];
    int t = threadIdx.x, b = blockIdx.x;
    int base = b * BCAP;
    int n = gcur[b] - base;
    bool inlds = (n <= SEGCAP);
    scnt[t] = 0;
    if (inlds) for (int i = t; i < n; i += 256) seg[i] = NTL(&ebuf[base + i]);
    __syncthreads();
    if (inlds) for (int i = t; i < n; i += 256) atomicAdd(&scnt[seg[i] >> 17], 1);
    else       for (int i = t; i < n; i += 256) atomicAdd(&scnt[NTL(&ebuf[base + i]) >> 17], 1);
    __syncthreads();
    int v = scnt[t];
    int v4 = (v + 3) & ~3;
    sloc[t] = v4;
    __syncthreads();
    for (int off = 1; off < 256; off <<= 1) {
        int a = (t >= off) ? sloc[t - off] : 0;
        __syncthreads();
        sloc[t] += a;
        __syncthreads();
    }
    int cur = b * PCAP + (sloc[t] - v4);
    int c = b * 256 + t;
    if (c < NN) {
        cursor[c] = cur;
        cnt[c]    = v;
        dis[c]    = rsqrtf((float)(v + 1));
    }
    run[t] = cur;
    __syncthreads();
    if (inlds) {
        for (int i = t; i < n; i += 256) {
            int pk = seg[i];
            int pos = atomicAdd(&run[pk >> 17], 1);
            csr_rid[pos] = pk & 0x1FFFF;          // plain: L2 merges runs
        }
    } else {
        for (int i = t; i < n; i += 256) {
            int pk = NTL(&ebuf[base + i]);
            int pos = atomicAdd(&run[pk >> 17], 1);
            csr_rid[pos] = pk & 0x1FFFF;
        }
    }
    __syncthreads();
    if (c < NN) {
        int p = cur + v, p4 = cur + v4;
        for (; p < p4; ++p) csr_rid[p] = NN;      // dummy -> zero feature row
    }
}

// ---- layer math ---------------------------------------------------------

// gh (fp16) = dis[node] * (x @ W1); x streamed NT (single use)
__global__ void __launch_bounds__(256) k_gemm1s(const float* __restrict__ x,
                                                const float* __restrict__ W1,
                                                const float* __restrict__ dis,
                                                __half* __restrict__ gh) {
    __shared__ float xs[32][CIN + 1];
    __shared__ float ws[CIN][CH];
    int t = threadIdx.x;
    int base = blockIdx.x * 32;                  // 100000 = 32*3125
    for (int i = t; i < CIN * CH; i += 256) ws[i >> 4][i & 15] = W1[i];
    const float4* xv = (const float4*)(x + (size_t)base * CIN);
    for (int i = t; i < 32 * CIN / 4; i += 256) {
        float4 v = ntl_f4(&xv[i]);
        int r = i >> 5, cq = i & 31;
        xs[r][cq * 4 + 0] = v.x; xs[r][cq * 4 + 1] = v.y;
        xs[r][cq * 4 + 2] = v.z; xs[r][cq * 4 + 3] = v.w;
    }
    __syncthreads();
    int node = t >> 3;
    int c0 = (t & 7) * 2;
    float a0 = 0.f, a1 = 0.f;
#pragma unroll 8
    for (int k = 0; k < CIN; ++k) {
        float xk = xs[node][k];
        a0 += xk * ws[k][c0];
        a1 += xk * ws[k][c0 + 1];
    }
    float d = dis[base + node];
    ((__half2*)gh)[((size_t)(base + node) * CH + c0) >> 1] = __floats2half2_rn(a0 * d, a1 * d);
}

__global__ void k_zrow(__half* __restrict__ gh, __half* __restrict__ g2h) {
    int t = threadIdx.x;
    if (t < CH) {
        gh [(size_t)NN * CH + t] = __float2half(0.f);
        g2h[(size_t)NN * CH + t] = __float2half(0.f);
    }
}

// add 8 fp16 channels (one float4 = 4 half2) into acc[8]
__device__ __forceinline__ void acc_h8(float4 raw, float* acc) {
    __half2 h0 = *(__half2*)&raw.x, h1 = *(__half2*)&raw.y;
    __half2 h2 = *(__half2*)&raw.z, h3 = *(__half2*)&raw.w;
    float2 f0 = __half22float2(h0), f1 = __half22float2(h1);
    float2 f2 = __half22float2(h2), f3 = __half22float2(h3);
    acc[0] += f0.x; acc[1] += f0.y; acc[2] += f1.x; acc[3] += f1.y;
    acc[4] += f2.x; acc[5] += f2.y; acc[6] += f3.x; acc[7] += f3.y;
}

// core accumulation over one node's edges given an int4 index stream
template <typename I4>
__device__ __forceinline__ void gather_loop(const I4 I, int nb, int h, int q,
                                            const float4* __restrict__ g8,
                                            float* acc) {
    int b = h;
    for (; b + 2 < nb; b += 4) {
        int4 i0 = I[b], i1 = I[b + 2];
        float4 v0 = g8[i0.x * 2 + q], v1 = g8[i0.y * 2 + q];
        float4 v2 = g8[i0.z * 2 + q], v3 = g8[i0.w * 2 + q];
        float4 w0 = g8[i1.x * 2 + q], w1 = g8[i1.y * 2 + q];
        float4 w2 = g8[i1.z * 2 + q], w3 = g8[i1.w * 2 + q];
        acc_h8(v0, acc); acc_h8(v1, acc); acc_h8(v2, acc); acc_h8(v3, acc);
        acc_h8(w0, acc); acc_h8(w1, acc); acc_h8(w2, acc); acc_h8(w3, acc);
    }
    for (; b < nb; b += 2) {
        int4 i0 = I[b];
        float4 v0 = g8[i0.x * 2 + q], v1 = g8[i0.y * 2 + q];
        float4 v2 = g8[i0.z * 2 + q], v3 = g8[i0.w * 2 + q];
        acc_h8(v0, acc); acc_h8(v1, acc); acc_h8(v2, acc); acc_h8(v3, acc);
    }
}

// 64 nodes/block, indices staged in LDS (NT from global)
__global__ void __launch_bounds__(256) k_gather1(const int* __restrict__ csr_rid,
                                                 const int* __restrict__ cursor,
                                                 const int* __restrict__ cnt,
                                                 const float* __restrict__ dis,
                                                 const __half* __restrict__ gh,
                                                 const float* __restrict__ b1,
                                                 __half* __restrict__ g2h) {
    __shared__ int ind[INDCAP];
    int t = threadIdx.x;
    int nbase = blockIdx.x * 64;
    int last  = min(nbase + 63, NN - 1);
    int start_all = cursor[nbase];
    int end_all   = cursor[last] + ((cnt[last] + 3) & ~3);
    int n_all = end_all - start_all;
    bool lds_ok = (n_all <= INDCAP);
    if (lds_ok) for (int i = t; i < n_all; i += 256) ind[i] = NTL(&csr_rid[start_all + i]);
    __syncthreads();
    int nl = t >> 2, q = t & 1, h = (t >> 1) & 1;
    int node = nbase + nl;
    if (node < NN) {
        const float4* g8 = (const float4*)gh;
        int myStart = cursor[node];
        int nb = (cnt[node] + 3) >> 2;
        float acc[8] = {0.f, 0.f, 0.f, 0.f, 0.f, 0.f, 0.f, 0.f};
        if (lds_ok) gather_loop((const int4*)&ind[myStart - start_all], nb, h, q, g8, acc);
        else        gather_loop((const int4*)(csr_rid + myStart),        nb, h, q, g8, acc);
#pragma unroll
        for (int j = 0; j < 8; ++j) acc[j] += __shfl_xor(acc[j], 2);
        if (h == 0) {
            acc_h8(g8[node * 2 + q], acc);       // self-loop
            float d = dis[node];
            const float4* b4 = (const float4*)b1;
            float4 bb0 = b4[q * 2], bb1 = b4[q * 2 + 1];
            float r0 = d * fmaxf(d * acc[0] + bb0.x, 0.f);
            float r1 = d * fmaxf(d * acc[1] + bb0.y, 0.f);
            float r2 = d * fmaxf(d * acc[2] + bb0.z, 0.f);
            float r3 = d * fmaxf(d * acc[3] + bb0.w, 0.f);
            float r4 = d * fmaxf(d * acc[4] + bb1.x, 0.f);
            float r5 = d * fmaxf(d * acc[5] + bb1.y, 0.f);
            float r6 = d * fmaxf(d * acc[6] + bb1.z, 0.f);
            float r7 = d * fmaxf(d * acc[7] + bb1.w, 0.f);
            __half2 p0 = __floats2half2_rn(r0, r1), p1 = __floats2half2_rn(r2, r3);
            __half2 p2 = __floats2half2_rn(r4, r5), p3 = __floats2half2_rn(r6, r7);
            uint4 wv;
            wv.x = *(unsigned int*)&p0; wv.y = *(unsigned int*)&p1;
            wv.z = *(unsigned int*)&p2; wv.w = *(unsigned int*)&p3;
            ((uint4*)g2h)[node * 2 + q] = wv;    // cached: gather2 reuses
        }
    }
}

// layer-2 gather fused with final GEMM + sigmoid; out streamed NT (coalesced)
__global__ void __launch_bounds__(256) k_gather2(const int* __restrict__ csr_rid,
                                                 const int* __restrict__ cursor,
                                                 const int* __restrict__ cnt,
                                                 const float* __restrict__ dis,
                                                 const __half* __restrict__ g2h,
                                                 const float* __restrict__ W2,
                                                 const float* __restrict__ b2,
                                                 float* __restrict__ out) {
    __shared__ int ind[INDCAP];
    __shared__ float vs[64][CH + 1];
    __shared__ float w2s[CH][CO];
    int t = threadIdx.x;
    for (int i = t; i < CH * CO; i += 256) w2s[i >> 6][i & 63] = W2[i];
    int nbase = blockIdx.x * 64;
    int last  = min(nbase + 63, NN - 1);
    int start_all = cursor[nbase];
    int end_all   = cursor[last] + ((cnt[last] + 3) & ~3);
    int n_all = end_all - start_all;
    bool lds_ok = (n_all <= INDCAP);
    if (lds_ok) for (int i = t; i < n_all; i += 256) ind[i] = NTL(&csr_rid[start_all + i]);
    __syncthreads();
    int nl = t >> 2, q = t & 1, h = (t >> 1) & 1;
    int node = nbase + nl;
    if (node < NN) {
        const float4* g8 = (const float4*)g2h;
        int myStart = cursor[node];
        int nb = (cnt[node] + 3) >> 2;
        float acc[8] = {0.f, 0.f, 0.f, 0.f, 0.f, 0.f, 0.f, 0.f};
        if (lds_ok) gather_loop((const int4*)&ind[myStart - start_all], nb, h, q, g8, acc);
        else        gather_loop((const int4*)(csr_rid + myStart),        nb, h, q, g8, acc);
#pragma unroll
        for (int j = 0; j < 8; ++j) acc[j] += __shfl_xor(acc[j], 2);
        if (h == 0) {
            acc_h8(g8[node * 2 + q], acc);       // self-loop
            float d = dis[node];
#pragma unroll
            for (int j = 0; j < 8; ++j) vs[nl][q * 8 + j] = d * acc[j];
        }
    }
    __syncthreads();
    int o = t & 63, grp = t >> 6;                // 4 groups x 16 nodes each
#pragma unroll
    for (int k = 0; k < 16; ++k) {
        int nl2 = grp * 16 + k;
        int node2 = nbase + nl2;
        if (node2 >= NN) break;
        float acc = b2[o];
#pragma unroll
        for (int c = 0; c < CH; ++c) acc += vs[nl2][c] * w2s[c][o];
        NTS(1.0f / (1.0f + __expf(-acc)), &out[(size_t)node2 * CO + o]);
    }
}

extern "C" void kernel_launch(void* const* d_in, const int* in_sizes, int n_in,
                              void* d_out, int out_size, void* d_ws, size_t ws_size,
                              hipStream_t stream) {
    const float* x  = (const float*)d_in[0];
    const int*   ei = (const int*)d_in[1];
    const float* W1 = (const float*)d_in[2];
    const float* b1 = (const float*)d_in[3];
    const float* W2 = (const float*)d_in[4];
    const float* b2 = (const float*)d_in[5];
    float* out = (float*)d_out;

    const int* rows = ei;
    const int* cols = ei + NE;

    char* w = (char*)d_ws;
    int*   cursor  = (int*)w;                 w += 100096 * 4;
    int*   cnt     = (int*)w;                 w += 100096 * 4;
    float* dis     = (float*)w;               w += 100096 * 4;
    int*   gcur    = (int*)w;                 w += 512 * 4;
    int*   ebuf    = (int*)w;                 w += (size_t)NBKT * BCAP * 4;   // 19.2 MB
    int*   csr_rid = (int*)w;                 // NBKT * PCAP ints = 20.4 MB
    // fp16 feature tables alias ebuf (ebuf dead after k_fine); NN+1 rows each
    __half* gh  = (__half*)ebuf;
    __half* g2h = gh + (size_t)(NN + 1) * CH;

    k_init   <<<1,    512, 0, stream>>>(gcur);
    k_part   <<<NBLK, 512, 0, stream>>>(rows, cols, gcur, ebuf);
    k_fine   <<<NBKT, 256, 0, stream>>>(ebuf, gcur, cursor, cnt, dis, csr_rid);
    k_gemm1s <<<NN / 32, 256, 0, stream>>>(x, W1, dis, gh);
    k_zrow   <<<1, 64, 0, stream>>>(gh, g2h);
    k_gather1<<<GBLK, 256, 0, stream>>>(csr_rid, cursor, cnt, dis, gh, b1, g2h);
    k_gather2<<<GBLK, 256, 0, stream>>>(csr_rid, cursor, cnt, dis, g2h, W2, b2, out);
}

// Round 17
// 131.275 us; speedup vs baseline: 1.7854x; 1.1417x over previous
//
#include <hip/hip_runtime.h>
#include <hip/hip_fp16.h>

constexpr int NN  = 100000;
constexpr int NE  = 3200000;
constexpr int CIN = 128;
constexpr int CH  = 16;   // hidden
constexpr int CO  = 64;   // out

constexpr int NBKT  = 391;    // ceil(NN/256): bucket = dest >> 8
constexpr int CHUNK = 4096;   // edges per block in bucketing passes
constexpr int NBLK  = 782;    // ceil(NE/CHUNK)
constexpr int SLACK = 772;    // per-bucket pad slack (768 max pad + 4 align)
constexpr int SEGCAP = 12288; // LDS staging cap for k_fine (48 KB)
constexpr int INDCAP = 4096;  // LDS index cap per 64-node gather block (16 KB)
constexpr int GBLK   = 1563;  // ceil(NN/64)

// ---- atomic-free CSR build ----------------------------------------------

__global__ void __launch_bounds__(256) k_hist(const int* __restrict__ cols,
                                              int* __restrict__ blkhist) {
    __shared__ int h[NBKT];
    int t = threadIdx.x, blk = blockIdx.x;
    for (int i = t; i < NBKT; i += 256) h[i] = 0;
    __syncthreads();
    const int4* c4 = (const int4*)cols;
    int base = blk * (CHUNK / 4);
#pragma unroll
    for (int j = 0; j < CHUNK / 4 / 256; ++j) {
        int idx = base + j * 256 + t;
        if (idx < NE / 4) {
            int4 c = c4[idx];
            atomicAdd(&h[c.x >> 8], 1); atomicAdd(&h[c.y >> 8], 1);
            atomicAdd(&h[c.z >> 8], 1); atomicAdd(&h[c.w >> 8], 1);
        }
    }
    __syncthreads();
    for (int i = t; i < NBKT; i += 256) blkhist[i * NBLK + blk] = h[i];
}

__global__ void __launch_bounds__(1024) k_rowscan(int* __restrict__ blkhist,
                                                  int* __restrict__ btot) {
    __shared__ int sh[1024];
    int t = threadIdx.x, b = blockIdx.x;
    int v = (t < NBLK) ? blkhist[b * NBLK + t] : 0;
    sh[t] = v;
    __syncthreads();
    for (int off = 1; off < 1024; off <<= 1) {
        int a = (t >= off) ? sh[t - off] : 0;
        __syncthreads();
        sh[t] += a;
        __syncthreads();
    }
    if (t < NBLK) blkhist[b * NBLK + t] = sh[t] - v;
    if (t == 1023) btot[b] = sh[1023];
}

__global__ void __launch_bounds__(512) k_bscan(const int* __restrict__ btot,
                                               int* __restrict__ bbase) {
    __shared__ int sh[512];
    int t = threadIdx.x;
    int v = (t < NBKT) ? btot[t] : 0;
    sh[t] = v;
    __syncthreads();
    for (int off = 1; off < 512; off <<= 1) {
        int a = (t >= off) ? sh[t - off] : 0;
        __syncthreads();
        sh[t] += a;
        __syncthreads();
    }
    if (t < NBKT) bbase[t] = sh[t] - v;
    if (t == NBKT - 1) bbase[NBKT] = sh[t];   // total == NE
}

// chunk -> LDS bucket-sort -> run-contiguous copy-out
__global__ void __launch_bounds__(512) k_sbucket(const int* __restrict__ rows,
                                                 const int* __restrict__ cols,
                                                 const int* __restrict__ blkhist,
                                                 const int* __restrict__ bbase,
                                                 int* __restrict__ ebuf) {
    __shared__ int sh[512];
    __shared__ int run[NBKT];
    __shared__ int tgt[NBKT];
    __shared__ int seg[CHUNK];
    __shared__ int gaddr[CHUNK];
    int t = threadIdx.x, blk = blockIdx.x;
    for (int i = t; i < NBKT; i += 512) run[i] = 0;
    __syncthreads();
    const int4* c4 = (const int4*)cols;
    const int4* r4 = (const int4*)rows;
    int base = blk * (CHUNK / 4);
#pragma unroll
    for (int j = 0; j < 2; ++j) {
        int idx = base + j * 512 + t;
        if (idx < NE / 4) {
            int4 c = c4[idx];
            atomicAdd(&run[c.x >> 8], 1); atomicAdd(&run[c.y >> 8], 1);
            atomicAdd(&run[c.z >> 8], 1); atomicAdd(&run[c.w >> 8], 1);
        }
    }
    __syncthreads();
    int v = (t < NBKT) ? run[t] : 0;
    sh[t] = v;
    __syncthreads();
    for (int off = 1; off < 512; off <<= 1) {
        int a = (t >= off) ? sh[t - off] : 0;
        __syncthreads();
        sh[t] += a;
        __syncthreads();
    }
    if (t < NBKT) {
        int excl = sh[t] - v;
        run[t] = excl;
        tgt[t] = bbase[t] + blkhist[t * NBLK + blk] - excl;
    }
    __syncthreads();
#pragma unroll
    for (int j = 0; j < 2; ++j) {
        int idx = base + j * 512 + t;
        if (idx < NE / 4) {
            int4 r = r4[idx];
            int4 c = c4[idx];
            int b0, p;
            b0 = c.x >> 8; p = atomicAdd(&run[b0], 1); seg[p] = r.x | ((c.x & 255) << 17); gaddr[p] = tgt[b0] + p;
            b0 = c.y >> 8; p = atomicAdd(&run[b0], 1); seg[p] = r.y | ((c.y & 255) << 17); gaddr[p] = tgt[b0] + p;
            b0 = c.z >> 8; p = atomicAdd(&run[b0], 1); seg[p] = r.z | ((c.z & 255) << 17); gaddr[p] = tgt[b0] + p;
            b0 = c.w >> 8; p = atomicAdd(&run[b0], 1); seg[p] = r.w | ((c.w & 255) << 17); gaddr[p] = tgt[b0] + p;
        }
    }
    __syncthreads();
    int n = min(CHUNK, NE - blk * CHUNK);
    for (int j = t; j < n; j += 512) ebuf[gaddr[j]] = seg[j];
}

// one block per bucket: LDS-staged count -> padded scan -> place -> pad-fill
__global__ void __launch_bounds__(256) k_fine(const int* __restrict__ ebuf,
                                              const int* __restrict__ bbase,
                                              int* __restrict__ cursor,
                                              int* __restrict__ cnt,
                                              float* __restrict__ dis,
                                              int* __restrict__ csr_rid) {
    __shared__ int seg[SEGCAP];
    __shared__ int scnt[256], sloc[256], run[256];
    int t = threadIdx.x, b = blockIdx.x;
    int base = bbase[b], n = bbase[b + 1] - base;
    bool inlds = (n <= SEGCAP);
    scnt[t] = 0;
    if (inlds) for (int i = t; i < n; i += 256) seg[i] = ebuf[base + i];
    __syncthreads();
    if (inlds) for (int i = t; i < n; i += 256) atomicAdd(&scnt[seg[i] >> 17], 1);
    else       for (int i = t; i < n; i += 256) atomicAdd(&scnt[ebuf[base + i] >> 17], 1);
    __syncthreads();
    int v = scnt[t];
    int v4 = (v + 3) & ~3;
    sloc[t] = v4;
    __syncthreads();
    for (int off = 1; off < 256; off <<= 1) {
        int a = (t >= off) ? sloc[t - off] : 0;
        __syncthreads();
        sloc[t] += a;
        __syncthreads();
    }
    int pb = ((base + 3) & ~3) + SLACK * b;
    int cur = pb + (sloc[t] - v4);
    int c = b * 256 + t;
    if (c < NN) {
        cursor[c] = cur;
        cnt[c]    = v;
        dis[c]    = rsqrtf((float)(v + 1));
    }
    run[t] = cur;
    __syncthreads();
    if (inlds) {
        for (int i = t; i < n; i += 256) {
            int pk = seg[i];
            int pos = atomicAdd(&run[pk >> 17], 1);
            csr_rid[pos] = pk & 0x1FFFF;
        }
    } else {
        for (int i = t; i < n; i += 256) {
            int pk = ebuf[base + i];
            int pos = atomicAdd(&run[pk >> 17], 1);
            csr_rid[pos] = pk & 0x1FFFF;
        }
    }
    __syncthreads();
    if (c < NN) {
        int p = cur + v, p4 = cur + v4;
        for (; p < p4; ++p) csr_rid[p] = NN;  // dummy -> zero feature row
    }
}

// ---- layer math ---------------------------------------------------------

// gh (fp16) = dis[node] * (x @ W1)
__global__ void __launch_bounds__(256) k_gemm1s(const float* __restrict__ x,
                                                const float* __restrict__ W1,
                                                const float* __restrict__ dis,
                                                __half* __restrict__ gh) {
    __shared__ float xs[32][CIN + 1];
    __shared__ float ws[CIN][CH];
    int t = threadIdx.x;
    int base = blockIdx.x * 32;                  // 100000 = 32*3125
    for (int i = t; i < CIN * CH; i += 256) ws[i >> 4][i & 15] = W1[i];
    const float4* xv = (const float4*)(x + (size_t)base * CIN);
    for (int i = t; i < 32 * CIN / 4; i += 256) {
        float4 v = xv[i];
        int r = i >> 5, cq = i & 31;
        xs[r][cq * 4 + 0] = v.x; xs[r][cq * 4 + 1] = v.y;
        xs[r][cq * 4 + 2] = v.z; xs[r][cq * 4 + 3] = v.w;
    }
    __syncthreads();
    int node = t >> 3;
    int c0 = (t & 7) * 2;
    float a0 = 0.f, a1 = 0.f;
#pragma unroll 8
    for (int k = 0; k < CIN; ++k) {
        float xk = xs[node][k];
        a0 += xk * ws[k][c0];
        a1 += xk * ws[k][c0 + 1];
    }
    float d = dis[base + node];
    ((__half2*)gh)[((size_t)(base + node) * CH + c0) >> 1] = __floats2half2_rn(a0 * d, a1 * d);
}

__global__ void k_zrow(__half* __restrict__ gh, __half* __restrict__ g2h) {
    int t = threadIdx.x;
    if (t < CH) {
        gh [(size_t)NN * CH + t] = __float2half(0.f);
        g2h[(size_t)NN * CH + t] = __float2half(0.f);
    }
}

// add 8 fp16 channels (one float4 = 4 half2) into acc[8]
__device__ __forceinline__ void acc_h8(float4 raw, float* acc) {
    __half2 h0 = *(__half2*)&raw.x, h1 = *(__half2*)&raw.y;
    __half2 h2 = *(__half2*)&raw.z, h3 = *(__half2*)&raw.w;
    float2 f0 = __half22float2(h0), f1 = __half22float2(h1);
    float2 f2 = __half22float2(h2), f3 = __half22float2(h3);
    acc[0] += f0.x; acc[1] += f0.y; acc[2] += f1.x; acc[3] += f1.y;
    acc[4] += f2.x; acc[5] += f2.y; acc[6] += f3.x; acc[7] += f3.y;
}

// core accumulation over one node's edges given an int4 index stream
template <typename I4>
__device__ __forceinline__ void gather_loop(const I4 I, int nb, int h, int q,
                                            const float4* __restrict__ g8,
                                            float* acc) {
    int b = h;
    for (; b + 2 < nb; b += 4) {
        int4 i0 = I[b], i1 = I[b + 2];
        float4 v0 = g8[i0.x * 2 + q], v1 = g8[i0.y * 2 + q];
        float4 v2 = g8[i0.z * 2 + q], v3 = g8[i0.w * 2 + q];
        float4 w0 = g8[i1.x * 2 + q], w1 = g8[i1.y * 2 + q];
        float4 w2 = g8[i1.z * 2 + q], w3 = g8[i1.w * 2 + q];
        acc_h8(v0, acc); acc_h8(v1, acc); acc_h8(v2, acc); acc_h8(v3, acc);
        acc_h8(w0, acc); acc_h8(w1, acc); acc_h8(w2, acc); acc_h8(w3, acc);
    }
    for (; b < nb; b += 2) {
        int4 i0 = I[b];
        float4 v0 = g8[i0.x * 2 + q], v1 = g8[i0.y * 2 + q];
        float4 v2 = g8[i0.z * 2 + q], v3 = g8[i0.w * 2 + q];
        acc_h8(v0, acc); acc_h8(v1, acc); acc_h8(v2, acc); acc_h8(v3, acc);
    }
}

// 64 nodes/block, indices staged in LDS; 4 lanes/node: q = ch half, h = edge half
__global__ void __launch_bounds__(256) k_gather1(const int* __restrict__ csr_rid,
                                                 const int* __restrict__ cursor,
                                                 const int* __restrict__ cnt,
                                                 const float* __restrict__ dis,
                                                 const __half* __restrict__ gh,
                                                 const float* __restrict__ b1,
                                                 __half* __restrict__ g2h) {
    __shared__ int ind[INDCAP];
    int t = threadIdx.x;
    int nbase = blockIdx.x * 64;
    int last  = min(nbase + 63, NN - 1);
    int start_all = cursor[nbase];
    int end_all   = cursor[last] + ((cnt[last] + 3) & ~3);
    int n_all = end_all - start_all;
    bool lds_ok = (n_all <= INDCAP);
    if (lds_ok) for (int i = t; i < n_all; i += 256) ind[i] = csr_rid[start_all + i];
    __syncthreads();
    int nl = t >> 2, q = t & 1, h = (t >> 1) & 1;
    int node = nbase + nl;
    if (node < NN) {
        const float4* g8 = (const float4*)gh;
        int myStart = cursor[node];
        int nb = (cnt[node] + 3) >> 2;
        float acc[8] = {0.f, 0.f, 0.f, 0.f, 0.f, 0.f, 0.f, 0.f};
        if (lds_ok) gather_loop((const int4*)&ind[myStart - start_all], nb, h, q, g8, acc);
        else        gather_loop((const int4*)(csr_rid + myStart),        nb, h, q, g8, acc);
#pragma unroll
        for (int j = 0; j < 8; ++j) acc[j] += __shfl_xor(acc[j], 2);
        if (h == 0) {
            acc_h8(g8[node * 2 + q], acc);       // self-loop
            float d = dis[node];
            const float4* b4 = (const float4*)b1;
            float4 bb0 = b4[q * 2], bb1 = b4[q * 2 + 1];
            float r0 = d * fmaxf(d * acc[0] + bb0.x, 0.f);
            float r1 = d * fmaxf(d * acc[1] + bb0.y, 0.f);
            float r2 = d * fmaxf(d * acc[2] + bb0.z, 0.f);
            float r3 = d * fmaxf(d * acc[3] + bb0.w, 0.f);
            float r4 = d * fmaxf(d * acc[4] + bb1.x, 0.f);
            float r5 = d * fmaxf(d * acc[5] + bb1.y, 0.f);
            float r6 = d * fmaxf(d * acc[6] + bb1.z, 0.f);
            float r7 = d * fmaxf(d * acc[7] + bb1.w, 0.f);
            __half2 p0 = __floats2half2_rn(r0, r1), p1 = __floats2half2_rn(r2, r3);
            __half2 p2 = __floats2half2_rn(r4, r5), p3 = __floats2half2_rn(r6, r7);
            uint4 wv;
            wv.x = *(unsigned int*)&p0; wv.y = *(unsigned int*)&p1;
            wv.z = *(unsigned int*)&p2; wv.w = *(unsigned int*)&p3;
            ((uint4*)g2h)[node * 2 + q] = wv;
        }
    }
}

// layer-2 gather (LDS-staged indices) fused with final GEMM + sigmoid
__global__ void __launch_bounds__(256) k_gather2(const int* __restrict__ csr_rid,
                                                 const int* __restrict__ cursor,
                                                 const int* __restrict__ cnt,
                                                 const float* __restrict__ dis,
                                                 const __half* __restrict__ g2h,
                                                 const float* __restrict__ W2,
                                                 const float* __restrict__ b2,
                                                 float* __restrict__ out) {
    __shared__ int ind[INDCAP];
    __shared__ float vs[64][CH + 1];
    __shared__ float w2s[CH][CO];
    int t = threadIdx.x;
    for (int i = t; i < CH * CO; i += 256) w2s[i >> 6][i & 63] = W2[i];
    int nbase = blockIdx.x * 64;
    int last  = min(nbase + 63, NN - 1);
    int start_all = cursor[nbase];
    int end_all   = cursor[last] + ((cnt[last] + 3) & ~3);
    int n_all = end_all - start_all;
    bool lds_ok = (n_all <= INDCAP);
    if (lds_ok) for (int i = t; i < n_all; i += 256) ind[i] = csr_rid[start_all + i];
    __syncthreads();
    int nl = t >> 2, q = t & 1, h = (t >> 1) & 1;
    int node = nbase + nl;
    if (node < NN) {
        const float4* g8 = (const float4*)g2h;
        int myStart = cursor[node];
        int nb = (cnt[node] + 3) >> 2;
        float acc[8] = {0.f, 0.f, 0.f, 0.f, 0.f, 0.f, 0.f, 0.f};
        if (lds_ok) gather_loop((const int4*)&ind[myStart - start_all], nb, h, q, g8, acc);
        else        gather_loop((const int4*)(csr_rid + myStart),        nb, h, q, g8, acc);
#pragma unroll
        for (int j = 0; j < 8; ++j) acc[j] += __shfl_xor(acc[j], 2);
        if (h == 0) {
            acc_h8(g8[node * 2 + q], acc);       // self-loop
            float d = dis[node];
#pragma unroll
            for (int j = 0; j < 8; ++j) vs[nl][q * 8 + j] = d * acc[j];
        }
    }
    __syncthreads();
    int o = t & 63, grp = t >> 6;                // 4 groups x 16 nodes each
#pragma unroll
    for (int k = 0; k < 16; ++k) {
        int nl2 = grp * 16 + k;
        int node2 = nbase + nl2;
        if (node2 >= NN) break;
        float acc = b2[o];
#pragma unroll
        for (int c = 0; c < CH; ++c) acc += vs[nl2][c] * w2s[c][o];
        out[(size_t)node2 * CO + o] = 1.0f / (1.0f + __expf(-acc));
    }
}

extern "C" void kernel_launch(void* const* d_in, const int* in_sizes, int n_in,
                              void* d_out, int out_size, void* d_ws, size_t ws_size,
                              hipStream_t stream) {
    const float* x  = (const float*)d_in[0];
    const int*   ei = (const int*)d_in[1];
    const float* W1 = (const float*)d_in[2];
    const float* b1 = (const float*)d_in[3];
    const float* W2 = (const float*)d_in[4];
    const float* b2 = (const float*)d_in[5];
    float* out = (float*)d_out;

    const int* rows = ei;
    const int* cols = ei + NE;

    char* w = (char*)d_ws;
    int*   cursor  = (int*)w;                 w += 100096 * 4;
    int*   cnt     = (int*)w;                 w += 100096 * 4;
    float* dis     = (float*)w;               w += 100096 * 4;
    int*   btot    = (int*)w;                 w += 512 * 4;
    int*   bbase   = (int*)w;                 w += 512 * 4;
    int*   ebuf    = (int*)w;                 w += (size_t)NE * 4;
    int*   csr_rid = (int*)w;                 // NE + SLACK*NBKT + 3 ints (padded)
    int*    blkhist = csr_rid;                // alias (dead before k_fine writes)
    __half* gh  = (__half*)ebuf;              // alias (ebuf dead after k_fine)
    __half* g2h = gh + (size_t)(NN + 1) * CH;

    k_hist   <<<NBLK, 256,  0, stream>>>(cols, blkhist);
    k_rowscan<<<NBKT, 1024, 0, stream>>>(blkhist, btot);
    k_bscan  <<<1,    512,  0, stream>>>(btot, bbase);
    k_sbucket<<<NBLK, 512,  0, stream>>>(rows, cols, blkhist, bbase, ebuf);
    k_fine   <<<NBKT, 256,  0, stream>>>(ebuf, bbase, cursor, cnt, dis, csr_rid);
    k_gemm1s <<<NN / 32, 256, 0, stream>>>(x, W1, dis, gh);
    k_zrow   <<<1, 64, 0, stream>>>(gh, g2h);
    k_gather1<<<GBLK, 256, 0, stream>>>(csr_rid, cursor, cnt, dis, gh, b1, g2h);
    k_gather2<<<GBLK, 256, 0, stream>>>(csr_rid, cursor, cnt, dis, g2h, W2, b2, out);
}

// Round 18
// 131.214 us; speedup vs baseline: 1.7862x; 1.0005x over previous
//
#include <hip/hip_runtime.h>
#include <hip/hip_fp16.h>

constexpr int NN  = 100000;
constexpr int NE  = 3200000;
constexpr int CIN = 128;
constexpr int CH  = 16;   // hidden
constexpr int CO  = 64;   // out

constexpr int NBKT  = 391;    // ceil(NN/256): bucket = dest >> 8
constexpr int CHUNK = 4096;   // edges per block in bucketing passes
constexpr int NBLK  = 782;    // ceil(NE/CHUNK)
constexpr int SLACK = 772;    // per-bucket pad slack (768 max pad + 4 align)
constexpr int SEGCAP = 12288; // LDS staging cap for k_fine (48 KB)
constexpr int INDCAP = 4096;  // LDS index cap per 64-node gather block (16 KB)
constexpr int GBLK   = 1563;  // ceil(NN/64)

typedef float ef2 __attribute__((ext_vector_type(2)));

// ---- atomic-free CSR build (unchanged from R17) --------------------------

__global__ void __launch_bounds__(256) k_hist(const int* __restrict__ cols,
                                              int* __restrict__ blkhist) {
    __shared__ int h[NBKT];
    int t = threadIdx.x, blk = blockIdx.x;
    for (int i = t; i < NBKT; i += 256) h[i] = 0;
    __syncthreads();
    const int4* c4 = (const int4*)cols;
    int base = blk * (CHUNK / 4);
#pragma unroll
    for (int j = 0; j < CHUNK / 4 / 256; ++j) {
        int idx = base + j * 256 + t;
        if (idx < NE / 4) {
            int4 c = c4[idx];
            atomicAdd(&h[c.x >> 8], 1); atomicAdd(&h[c.y >> 8], 1);
            atomicAdd(&h[c.z >> 8], 1); atomicAdd(&h[c.w >> 8], 1);
        }
    }
    __syncthreads();
    for (int i = t; i < NBKT; i += 256) blkhist[i * NBLK + blk] = h[i];
}

__global__ void __launch_bounds__(1024) k_rowscan(int* __restrict__ blkhist,
                                                  int* __restrict__ btot) {
    __shared__ int sh[1024];
    int t = threadIdx.x, b = blockIdx.x;
    int v = (t < NBLK) ? blkhist[b * NBLK + t] : 0;
    sh[t] = v;
    __syncthreads();
    for (int off = 1; off < 1024; off <<= 1) {
        int a = (t >= off) ? sh[t - off] : 0;
        __syncthreads();
        sh[t] += a;
        __syncthreads();
    }
    if (t < NBLK) blkhist[b * NBLK + t] = sh[t] - v;
    if (t == 1023) btot[b] = sh[1023];
}

__global__ void __launch_bounds__(512) k_bscan(const int* __restrict__ btot,
                                               int* __restrict__ bbase) {
    __shared__ int sh[512];
    int t = threadIdx.x;
    int v = (t < NBKT) ? btot[t] : 0;
    sh[t] = v;
    __syncthreads();
    for (int off = 1; off < 512; off <<= 1) {
        int a = (t >= off) ? sh[t - off] : 0;
        __syncthreads();
        sh[t] += a;
        __syncthreads();
    }
    if (t < NBKT) bbase[t] = sh[t] - v;
    if (t == NBKT - 1) bbase[NBKT] = sh[t];   // total == NE
}

// chunk -> LDS bucket-sort -> run-contiguous copy-out
__global__ void __launch_bounds__(512) k_sbucket(const int* __restrict__ rows,
                                                 const int* __restrict__ cols,
                                                 const int* __restrict__ blkhist,
                                                 const int* __restrict__ bbase,
                                                 int* __restrict__ ebuf) {
    __shared__ int sh[512];
    __shared__ int run[NBKT];
    __shared__ int tgt[NBKT];
    __shared__ int seg[CHUNK];
    __shared__ int gaddr[CHUNK];
    int t = threadIdx.x, blk = blockIdx.x;
    for (int i = t; i < NBKT; i += 512) run[i] = 0;
    __syncthreads();
    const int4* c4 = (const int4*)cols;
    const int4* r4 = (const int4*)rows;
    int base = blk * (CHUNK / 4);
#pragma unroll
    for (int j = 0; j < 2; ++j) {
        int idx = base + j * 512 + t;
        if (idx < NE / 4) {
            int4 c = c4[idx];
            atomicAdd(&run[c.x >> 8], 1); atomicAdd(&run[c.y >> 8], 1);
            atomicAdd(&run[c.z >> 8], 1); atomicAdd(&run[c.w >> 8], 1);
        }
    }
    __syncthreads();
    int v = (t < NBKT) ? run[t] : 0;
    sh[t] = v;
    __syncthreads();
    for (int off = 1; off < 512; off <<= 1) {
        int a = (t >= off) ? sh[t - off] : 0;
        __syncthreads();
        sh[t] += a;
        __syncthreads();
    }
    if (t < NBKT) {
        int excl = sh[t] - v;
        run[t] = excl;
        tgt[t] = bbase[t] + blkhist[t * NBLK + blk] - excl;
    }
    __syncthreads();
#pragma unroll
    for (int j = 0; j < 2; ++j) {
        int idx = base + j * 512 + t;
        if (idx < NE / 4) {
            int4 r = r4[idx];
            int4 c = c4[idx];
            int b0, p;
            b0 = c.x >> 8; p = atomicAdd(&run[b0], 1); seg[p] = r.x | ((c.x & 255) << 17); gaddr[p] = tgt[b0] + p;
            b0 = c.y >> 8; p = atomicAdd(&run[b0], 1); seg[p] = r.y | ((c.y & 255) << 17); gaddr[p] = tgt[b0] + p;
            b0 = c.z >> 8; p = atomicAdd(&run[b0], 1); seg[p] = r.z | ((c.z & 255) << 17); gaddr[p] = tgt[b0] + p;
            b0 = c.w >> 8; p = atomicAdd(&run[b0], 1); seg[p] = r.w | ((c.w & 255) << 17); gaddr[p] = tgt[b0] + p;
        }
    }
    __syncthreads();
    int n = min(CHUNK, NE - blk * CHUNK);
    for (int j = t; j < n; j += 512) ebuf[gaddr[j]] = seg[j];
}

// one block per bucket: LDS-staged count -> padded scan -> place -> pad-fill
__global__ void __launch_bounds__(256) k_fine(const int* __restrict__ ebuf,
                                              const int* __restrict__ bbase,
                                              int* __restrict__ cursor,
                                              int* __restrict__ cnt,
                                              float* __restrict__ dis,
                                              int* __restrict__ csr_rid) {
    __shared__ int seg[SEGCAP];
    __shared__ int scnt[256], sloc[256], run[256];
    int t = threadIdx.x, b = blockIdx.x;
    int base = bbase[b], n = bbase[b + 1] - base;
    bool inlds = (n <= SEGCAP);
    scnt[t] = 0;
    if (inlds) for (int i = t; i < n; i += 256) seg[i] = ebuf[base + i];
    __syncthreads();
    if (inlds) for (int i = t; i < n; i += 256) atomicAdd(&scnt[seg[i] >> 17], 1);
    else       for (int i = t; i < n; i += 256) atomicAdd(&scnt[ebuf[base + i] >> 17], 1);
    __syncthreads();
    int v = scnt[t];
    int v4 = (v + 3) & ~3;
    sloc[t] = v4;
    __syncthreads();
    for (int off = 1; off < 256; off <<= 1) {
        int a = (t >= off) ? sloc[t - off] : 0;
        __syncthreads();
        sloc[t] += a;
        __syncthreads();
    }
    int pb = ((base + 3) & ~3) + SLACK * b;
    int cur = pb + (sloc[t] - v4);
    int c = b * 256 + t;
    if (c < NN) {
        cursor[c] = cur;
        cnt[c]    = v;
        dis[c]    = rsqrtf((float)(v + 1));
    }
    run[t] = cur;
    __syncthreads();
    if (inlds) {
        for (int i = t; i < n; i += 256) {
            int pk = seg[i];
            int pos = atomicAdd(&run[pk >> 17], 1);
            csr_rid[pos] = pk & 0x1FFFF;
        }
    } else {
        for (int i = t; i < n; i += 256) {
            int pk = ebuf[base + i];
            int pos = atomicAdd(&run[pk >> 17], 1);
            csr_rid[pos] = pk & 0x1FFFF;
        }
    }
    __syncthreads();
    if (c < NN) {
        int p = cur + v, p4 = cur + v4;
        for (; p < p4; ++p) csr_rid[p] = NN;  // dummy -> zero feature row
    }
}

// ---- layer math ---------------------------------------------------------

// gh (fp16) = dis[node] * (x @ W1)
__global__ void __launch_bounds__(256) k_gemm1s(const float* __restrict__ x,
                                                const float* __restrict__ W1,
                                                const float* __restrict__ dis,
                                                __half* __restrict__ gh) {
    __shared__ float xs[32][CIN + 1];
    __shared__ float ws[CIN][CH];
    int t = threadIdx.x;
    int base = blockIdx.x * 32;                  // 100000 = 32*3125
    for (int i = t; i < CIN * CH; i += 256) ws[i >> 4][i & 15] = W1[i];
    const float4* xv = (const float4*)(x + (size_t)base * CIN);
    for (int i = t; i < 32 * CIN / 4; i += 256) {
        float4 v = xv[i];
        int r = i >> 5, cq = i & 31;
        xs[r][cq * 4 + 0] = v.x; xs[r][cq * 4 + 1] = v.y;
        xs[r][cq * 4 + 2] = v.z; xs[r][cq * 4 + 3] = v.w;
    }
    __syncthreads();
    int node = t >> 3;
    int c0 = (t & 7) * 2;
    float a0 = 0.f, a1 = 0.f;
#pragma unroll 8
    for (int k = 0; k < CIN; ++k) {
        float xk = xs[node][k];
        a0 += xk * ws[k][c0];
        a1 += xk * ws[k][c0 + 1];
    }
    float d = dis[base + node];
    ((__half2*)gh)[((size_t)(base + node) * CH + c0) >> 1] = __floats2half2_rn(a0 * d, a1 * d);
}

__global__ void k_zrow(__half* __restrict__ gh, unsigned int* __restrict__ g2f8) {
    int t = threadIdx.x;
    if (t < CH) gh[(size_t)NN * CH + t] = __float2half(0.f);
    if (t < 4)  g2f8[(size_t)NN * 4 + t] = 0u;   // fp8 zero row (16 B)
}

// add 8 fp16 channels (one float4 = 4 half2) into acc[8]
__device__ __forceinline__ void acc_h8(float4 raw, float* acc) {
    __half2 h0 = *(__half2*)&raw.x, h1 = *(__half2*)&raw.y;
    __half2 h2 = *(__half2*)&raw.z, h3 = *(__half2*)&raw.w;
    float2 f0 = __half22float2(h0), f1 = __half22float2(h1);
    float2 f2 = __half22float2(h2), f3 = __half22float2(h3);
    acc[0] += f0.x; acc[1] += f0.y; acc[2] += f1.x; acc[3] += f1.y;
    acc[4] += f2.x; acc[5] += f2.y; acc[6] += f3.x; acc[7] += f3.y;
}

// decode 16 fp8 e4m3 (one uint4) and accumulate into acc[16]
__device__ __forceinline__ void dec16(uint4 U, float* acc) {
    ef2 f;
    f = __builtin_amdgcn_cvt_pk_f32_fp8((int)U.x, false); acc[0]  += f.x; acc[1]  += f.y;
    f = __builtin_amdgcn_cvt_pk_f32_fp8((int)U.x, true);  acc[2]  += f.x; acc[3]  += f.y;
    f = __builtin_amdgcn_cvt_pk_f32_fp8((int)U.y, false); acc[4]  += f.x; acc[5]  += f.y;
    f = __builtin_amdgcn_cvt_pk_f32_fp8((int)U.y, true);  acc[6]  += f.x; acc[7]  += f.y;
    f = __builtin_amdgcn_cvt_pk_f32_fp8((int)U.z, false); acc[8]  += f.x; acc[9]  += f.y;
    f = __builtin_amdgcn_cvt_pk_f32_fp8((int)U.z, true);  acc[10] += f.x; acc[11] += f.y;
    f = __builtin_amdgcn_cvt_pk_f32_fp8((int)U.w, false); acc[12] += f.x; acc[13] += f.y;
    f = __builtin_amdgcn_cvt_pk_f32_fp8((int)U.w, true);  acc[14] += f.x; acc[15] += f.y;
}

// core fp16 accumulation over one node's edges given an int4 index stream
template <typename I4>
__device__ __forceinline__ void gather_loop(const I4 I, int nb, int h, int q,
                                            const float4* __restrict__ g8,
                                            float* acc) {
    int b = h;
    for (; b + 2 < nb; b += 4) {
        int4 i0 = I[b], i1 = I[b + 2];
        float4 v0 = g8[i0.x * 2 + q], v1 = g8[i0.y * 2 + q];
        float4 v2 = g8[i0.z * 2 + q], v3 = g8[i0.w * 2 + q];
        float4 w0 = g8[i1.x * 2 + q], w1 = g8[i1.y * 2 + q];
        float4 w2 = g8[i1.z * 2 + q], w3 = g8[i1.w * 2 + q];
        acc_h8(v0, acc); acc_h8(v1, acc); acc_h8(v2, acc); acc_h8(v3, acc);
        acc_h8(w0, acc); acc_h8(w1, acc); acc_h8(w2, acc); acc_h8(w3, acc);
    }
    for (; b < nb; b += 2) {
        int4 i0 = I[b];
        float4 v0 = g8[i0.x * 2 + q], v1 = g8[i0.y * 2 + q];
        float4 v2 = g8[i0.z * 2 + q], v3 = g8[i0.w * 2 + q];
        acc_h8(v0, acc); acc_h8(v1, acc); acc_h8(v2, acc); acc_h8(v3, acc);
    }
}

// layer-1 gather: fp16 table in, fp8 e4m3 table out
__global__ void __launch_bounds__(256) k_gather1(const int* __restrict__ csr_rid,
                                                 const int* __restrict__ cursor,
                                                 const int* __restrict__ cnt,
                                                 const float* __restrict__ dis,
                                                 const __half* __restrict__ gh,
                                                 const float* __restrict__ b1,
                                                 unsigned int* __restrict__ g2f8) {
    __shared__ int ind[INDCAP];
    int t = threadIdx.x;
    int nbase = blockIdx.x * 64;
    int last  = min(nbase + 63, NN - 1);
    int start_all = cursor[nbase];
    int end_all   = cursor[last] + ((cnt[last] + 3) & ~3);
    int n_all = end_all - start_all;
    bool lds_ok = (n_all <= INDCAP);
    if (lds_ok) for (int i = t; i < n_all; i += 256) ind[i] = csr_rid[start_all + i];
    __syncthreads();
    int nl = t >> 2, q = t & 1, h = (t >> 1) & 1;
    int node = nbase + nl;
    if (node < NN) {
        const float4* g8 = (const float4*)gh;
        int myStart = cursor[node];
        int nb = (cnt[node] + 3) >> 2;
        float acc[8] = {0.f, 0.f, 0.f, 0.f, 0.f, 0.f, 0.f, 0.f};
        if (lds_ok) gather_loop((const int4*)&ind[myStart - start_all], nb, h, q, g8, acc);
        else        gather_loop((const int4*)(csr_rid + myStart),        nb, h, q, g8, acc);
#pragma unroll
        for (int j = 0; j < 8; ++j) acc[j] += __shfl_xor(acc[j], 2);
        if (h == 0) {
            acc_h8(g8[node * 2 + q], acc);       // self-loop
            float d = dis[node];
            const float4* b4 = (const float4*)b1;
            float4 bb0 = b4[q * 2], bb1 = b4[q * 2 + 1];
            float r0 = d * fmaxf(d * acc[0] + bb0.x, 0.f);
            float r1 = d * fmaxf(d * acc[1] + bb0.y, 0.f);
            float r2 = d * fmaxf(d * acc[2] + bb0.z, 0.f);
            float r3 = d * fmaxf(d * acc[3] + bb0.w, 0.f);
            float r4 = d * fmaxf(d * acc[4] + bb1.x, 0.f);
            float r5 = d * fmaxf(d * acc[5] + bb1.y, 0.f);
            float r6 = d * fmaxf(d * acc[6] + bb1.z, 0.f);
            float r7 = d * fmaxf(d * acc[7] + bb1.w, 0.f);
            unsigned lo = __builtin_amdgcn_cvt_pk_fp8_f32(r0, r1, 0, false);
            lo = (unsigned)__builtin_amdgcn_cvt_pk_fp8_f32(r2, r3, (int)lo, true);
            unsigned hi = __builtin_amdgcn_cvt_pk_fp8_f32(r4, r5, 0, false);
            hi = (unsigned)__builtin_amdgcn_cvt_pk_fp8_f32(r6, r7, (int)hi, true);
            ((uint2*)g2f8)[node * 2 + q] = make_uint2(lo, hi);
        }
    }
}

// layer-2 gather: fp8 table, 1 request/edge, 4 lanes/node; fused GEMM + sigmoid
__global__ void __launch_bounds__(256) k_gather2(const int* __restrict__ csr_rid,
                                                 const int* __restrict__ cursor,
                                                 const int* __restrict__ cnt,
                                                 const float* __restrict__ dis,
                                                 const uint4* __restrict__ g2f8,
                                                 const float* __restrict__ W2,
                                                 const float* __restrict__ b2,
                                                 float* __restrict__ out) {
    __shared__ int ind[INDCAP];
    __shared__ float vs[64][CH + 1];
    __shared__ float w2s[CH][CO];
    int t = threadIdx.x;
    for (int i = t; i < CH * CO; i += 256) w2s[i >> 6][i & 63] = W2[i];
    int nbase = blockIdx.x * 64;
    int last  = min(nbase + 63, NN - 1);
    int start_all = cursor[nbase];
    int end_all   = cursor[last] + ((cnt[last] + 3) & ~3);
    int n_all = end_all - start_all;
    bool lds_ok = (n_all <= INDCAP);
    if (lds_ok) for (int i = t; i < n_all; i += 256) ind[i] = csr_rid[start_all + i];
    __syncthreads();
    int nl = t >> 2, h = t & 3;
    int node = nbase + nl;
    if (node < NN) {
        int myStart = cursor[node];
        int n4 = (cnt[node] + 3) & ~3;           // padded edge count
        float acc[16];
#pragma unroll
        for (int j = 0; j < 16; ++j) acc[j] = 0.f;
        const int* I = lds_ok ? &ind[myStart - start_all] : (csr_rid + myStart);
        int e = h;
        for (; e + 4 < n4; e += 8) {             // 2 feature loads in flight/lane
            int r0 = I[e], r1 = I[e + 4];
            uint4 U0 = g2f8[r0], U1 = g2f8[r1];
            dec16(U0, acc); dec16(U1, acc);
        }
        for (; e < n4; e += 4) dec16(g2f8[I[e]], acc);
#pragma unroll
        for (int j = 0; j < 16; ++j) {
            acc[j] += __shfl_xor(acc[j], 1);
            acc[j] += __shfl_xor(acc[j], 2);
        }
        if (h == 0) {
            dec16(g2f8[node], acc);              // self-loop
            float d = dis[node];
#pragma unroll
            for (int j = 0; j < 16; ++j) vs[nl][j] = d * acc[j];
        }
    }
    __syncthreads();
    int o = t & 63, grp = t >> 6;                // 4 groups x 16 nodes each
#pragma unroll
    for (int k = 0; k < 16; ++k) {
        int nl2 = grp * 16 + k;
        int node2 = nbase + nl2;
        if (node2 >= NN) break;
        float acc = b2[o];
#pragma unroll
        for (int c = 0; c < CH; ++c) acc += vs[nl2][c] * w2s[c][o];
        out[(size_t)node2 * CO + o] = 1.0f / (1.0f + __expf(-acc));
    }
}

extern "C" void kernel_launch(void* const* d_in, const int* in_sizes, int n_in,
                              void* d_out, int out_size, void* d_ws, size_t ws_size,
                              hipStream_t stream) {
    const float* x  = (const float*)d_in[0];
    const int*   ei = (const int*)d_in[1];
    const float* W1 = (const float*)d_in[2];
    const float* b1 = (const float*)d_in[3];
    const float* W2 = (const float*)d_in[4];
    const float* b2 = (const float*)d_in[5];
    float* out = (float*)d_out;

    const int* rows = ei;
    const int* cols = ei + NE;

    char* w = (char*)d_ws;
    int*   cursor  = (int*)w;                 w += 100096 * 4;
    int*   cnt     = (int*)w;                 w += 100096 * 4;
    float* dis     = (float*)w;               w += 100096 * 4;
    int*   btot    = (int*)w;                 w += 512 * 4;
    int*   bbase   = (int*)w;                 w += 512 * 4;
    int*   ebuf    = (int*)w;                 w += (size_t)NE * 4;
    int*   csr_rid = (int*)w;                 // NE + SLACK*NBKT + 3 ints (padded)
    int*    blkhist = csr_rid;                // alias (dead before k_fine writes)
    // feature tables alias ebuf (dead after k_fine): fp16 gh (3.2 MB) then fp8 g2f8 (1.6 MB)
    __half*       gh   = (__half*)ebuf;                       // (NN+1)*CH halves
    unsigned int* g2f8 = (unsigned int*)(gh + (size_t)(NN + 1) * CH);  // (NN+1)*4 uints

    k_hist   <<<NBLK, 256,  0, stream>>>(cols, blkhist);
    k_rowscan<<<NBKT, 1024, 0, stream>>>(blkhist, btot);
    k_bscan  <<<1,    512,  0, stream>>>(btot, bbase);
    k_sbucket<<<NBLK, 512,  0, stream>>>(rows, cols, blkhist, bbase, ebuf);
    k_fine   <<<NBKT, 256,  0, stream>>>(ebuf, bbase, cursor, cnt, dis, csr_rid);
    k_gemm1s <<<NN / 32, 256, 0, stream>>>(x, W1, dis, gh);
    k_zrow   <<<1, 64, 0, stream>>>(gh, g2f8);
    k_gather1<<<GBLK, 256, 0, stream>>>(csr_rid, cursor, cnt, dis, gh, b1, g2f8);
    k_gather2<<<GBLK, 256, 0, stream>>>(csr_rid, cursor, cnt, dis, (const uint4*)g2f8, W2, b2, out);
}